// Round 1
// baseline (1646.524 us; speedup 1.0000x reference)
//
#include <hip/hip_runtime.h>

#define DD 2048
#define SEQ 2048
#define NH 16
#define NKV 4
#define HD 128
#define FFD 5632
#define NL 2

typedef __bf16 bf16x8 __attribute__((ext_vector_type(8)));
typedef float f32x4 __attribute__((ext_vector_type(4)));

__device__ __forceinline__ unsigned short f2bf(float f) {
    unsigned int u = __builtin_bit_cast(unsigned int, f);
    u += 0x7fffu + ((u >> 16) & 1u);   // round-to-nearest-even
    return (unsigned short)(u >> 16);
}

// ---------------- embedding gather ----------------
__global__ __launch_bounds__(256)
void embed_gather(const int* __restrict__ ids, const float* __restrict__ wemb,
                  float* __restrict__ x)
{
    int s = blockIdx.x;
    int id = ids[s];
    const float4* src = (const float4*)(wemb + (size_t)id * DD);
    float4* dst = (float4*)(x + (size_t)s * DD);
    dst[threadIdx.x] = src[threadIdx.x];
    dst[threadIdx.x + 256] = src[threadIdx.x + 256];
}

// ---------------- fused RMSNorm -> bf16 ----------------
__global__ __launch_bounds__(256)
void rmsnorm_bf16(const float* __restrict__ x, const float* __restrict__ w,
                  unsigned short* __restrict__ out)
{
    int row = blockIdx.x;
    int t = threadIdx.x;
    const float4* xr = (const float4*)(x + (size_t)row * DD);
    float4 v0 = xr[t], v1 = xr[t + 256];
    float ss = v0.x * v0.x + v0.y * v0.y + v0.z * v0.z + v0.w * v0.w
             + v1.x * v1.x + v1.y * v1.y + v1.z * v1.z + v1.w * v1.w;
#pragma unroll
    for (int off = 32; off; off >>= 1) ss += __shfl_down(ss, off);
    __shared__ float red[4];
    if ((t & 63) == 0) red[t >> 6] = ss;
    __syncthreads();
    float sc = rsqrtf((red[0] + red[1] + red[2] + red[3]) * (1.0f / DD) + 1e-5f);
    const float4* wr = (const float4*)w;
    float4 w0 = wr[t], w1v = wr[t + 256];
    ushort4 o0, o1;
    o0.x = f2bf(v0.x * sc * w0.x);  o0.y = f2bf(v0.y * sc * w0.y);
    o0.z = f2bf(v0.z * sc * w0.z);  o0.w = f2bf(v0.w * sc * w0.w);
    o1.x = f2bf(v1.x * sc * w1v.x); o1.y = f2bf(v1.y * sc * w1v.y);
    o1.z = f2bf(v1.z * sc * w1v.z); o1.w = f2bf(v1.w * sc * w1v.w);
    ushort4* op = (ushort4*)(out + (size_t)row * DD);
    op[t] = o0;
    op[t + 256] = o1;
}

// ---------------- tiled transpose + fp32->bf16 cast ----------------
// src[r][c] (ld_src) -> dst[c][r] (ld_dst); grid = (C/32, R/32, batch)
__global__ __launch_bounds__(256)
void transpose_cast(const float* __restrict__ src, unsigned short* __restrict__ dst,
                    int ld_src, int ld_dst, size_t sb, size_t db)
{
    __shared__ float tile[32][33];
    src += (size_t)blockIdx.z * sb;
    dst += (size_t)blockIdx.z * db;
    int c0 = blockIdx.x * 32, r0 = blockIdx.y * 32;
    int tx = threadIdx.x & 31, ty = threadIdx.x >> 5;
#pragma unroll
    for (int i = 0; i < 4; ++i)
        tile[ty + i * 8][tx] = src[(size_t)(r0 + ty + i * 8) * ld_src + c0 + tx];
    __syncthreads();
#pragma unroll
    for (int i = 0; i < 4; ++i)
        dst[(size_t)(c0 + ty + i * 8) * ld_dst + r0 + tx] = f2bf(tile[tx][ty + i * 8]);
}

// ---------------- RoPE for q and k (writes head-major bf16) ----------------
// grid (S, NH+NKV), block 64 (one thread per rotation pair)
__global__ void rope_qk(const float* __restrict__ qkv, const float* __restrict__ fc,
                        unsigned short* __restrict__ Qb, unsigned short* __restrict__ Kb)
{
    int s = blockIdx.x;
    int hh = blockIdx.y;
    int i = threadIdx.x;  // 0..63
    float2 cs = *(const float2*)(fc + ((size_t)s * 64 + i) * 2);
    const float* src;
    unsigned short* dst;
    if (hh < NH) {
        src = qkv + (size_t)s * 3072 + hh * HD;
        dst = Qb + ((size_t)hh * SEQ + s) * HD;
    } else {
        int kh = hh - NH;
        src = qkv + (size_t)s * 3072 + DD + kh * HD;
        dst = Kb + ((size_t)kh * SEQ + s) * HD;
    }
    float2 xv = *(const float2*)(src + 2 * i);
    ushort2 o;
    o.x = f2bf(xv.x * cs.x - xv.y * cs.y);
    o.y = f2bf(xv.y * cs.x + xv.x * cs.y);
    *(ushort2*)(dst + 2 * i) = o;
}

// ---------------- SiLU(h1) * h3 -> bf16 ----------------
__global__ __launch_bounds__(256)
void silu_mul(const float* __restrict__ h, unsigned short* __restrict__ g)
{
    size_t i = (size_t)blockIdx.x * 256 + threadIdx.x;  // float4 groups
    size_t row = i / (FFD / 4), c4 = i % (FFD / 4);
    const float* p = h + row * (2 * FFD) + c4 * 4;
    float4 a = *(const float4*)(p);
    float4 b = *(const float4*)(p + FFD);
    ushort4 o;
    o.x = f2bf(a.x / (1.f + __expf(-a.x)) * b.x);
    o.y = f2bf(a.y / (1.f + __expf(-a.y)) * b.y);
    o.z = f2bf(a.z / (1.f + __expf(-a.z)) * b.z);
    o.w = f2bf(a.w / (1.f + __expf(-a.w)) * b.w);
    *(ushort4*)(g + row * FFD + c4 * 4) = o;
}

// ---------------- bf16 MFMA GEMM: C[M,N] = A[M,K] * W, B = W^T stored [N][K] ----
// 128x128 tile, BK=64, 4 waves (2x2), 16x16x32 MFMA, XOR-swizzled LDS.
__global__ __launch_bounds__(256)
void gemm_bf16(const unsigned short* __restrict__ A, const unsigned short* __restrict__ B,
               float* __restrict__ C, const float* __restrict__ Res,
               int N, int K)
{
    __shared__ __attribute__((aligned(16))) unsigned char smem[32768];
    const int tid = threadIdx.x;
    const int lane = tid & 63;
    const int w = tid >> 6;
    const int n0 = blockIdx.x * 128;
    const int m0 = blockIdx.y * 128;
    const int wm = (w >> 1) * 64, wn = (w & 1) * 64;
    const int lrow = lane & 15, lgrp = lane >> 4;

    f32x4 acc[4][4];
#pragma unroll
    for (int i = 0; i < 4; ++i)
#pragma unroll
        for (int j = 0; j < 4; ++j) acc[i][j] = 0.f;

    for (int kt = 0; kt < K; kt += 64) {
        __syncthreads();
#pragma unroll
        for (int it = 0; it < 4; ++it) {
            int o = it * 4096 + tid * 16;       // byte offset in 16KB tile
            int row = o >> 7, col = o & 127;    // row: 0..127, col bytes within 128B row
            int so = o ^ ((row & 7) << 4);
            bf16x8 va = *(const bf16x8*)((const char*)A + ((size_t)(m0 + row) * K + kt) * 2 + col);
            bf16x8 vb = *(const bf16x8*)((const char*)B + ((size_t)(n0 + row) * K + kt) * 2 + col);
            *(bf16x8*)(smem + so) = va;
            *(bf16x8*)(smem + 16384 + so) = vb;
        }
        __syncthreads();
#pragma unroll
        for (int kk = 0; kk < 2; ++kk) {
            bf16x8 af[4], bfr[4];
            int cb = kk * 64 + lgrp * 16;
#pragma unroll
            for (int i = 0; i < 4; ++i) {
                int ra = wm + i * 16 + lrow;
                af[i] = *(const bf16x8*)(smem + ra * 128 + (cb ^ ((ra & 7) << 4)));
                int rb = wn + i * 16 + lrow;
                bfr[i] = *(const bf16x8*)(smem + 16384 + rb * 128 + (cb ^ ((rb & 7) << 4)));
            }
#pragma unroll
            for (int i = 0; i < 4; ++i)
#pragma unroll
                for (int j = 0; j < 4; ++j)
                    acc[i][j] = __builtin_amdgcn_mfma_f32_16x16x32_bf16(af[i], bfr[j], acc[i][j], 0, 0, 0);
        }
    }

    const bool hasRes = (Res != nullptr);
#pragma unroll
    for (int i = 0; i < 4; ++i)
#pragma unroll
        for (int j = 0; j < 4; ++j) {
            int r = m0 + wm + i * 16 + lgrp * 4;
            int c = n0 + wn + j * 16 + lrow;
#pragma unroll
            for (int jj = 0; jj < 4; ++jj) {
                size_t idx = (size_t)(r + jj) * N + c;
                float v = acc[i][j][jj];
                if (hasRes) v += Res[idx];
                C[idx] = v;
            }
        }
}

// ---------------- flash attention (causal, GQA) ----------------
// grid (32 q-blocks [reversed], 16 heads), 256 threads = 4 waves x 16 q-rows.
// Q bf16 [NH][S][HD]; K bf16 [NKV][S][HD]; VT bf16 [NKV][HD][S]; O bf16 [S][DD]
__global__ __launch_bounds__(256)
void attn_fwd(const unsigned short* __restrict__ Qb, const unsigned short* __restrict__ Kb,
              const unsigned short* __restrict__ VTb, unsigned short* __restrict__ O)
{
    __shared__ __attribute__((aligned(16))) unsigned char smem[40960]; // K 16K | VT 16K | P 4x2K
    const int qb = 31 - (int)blockIdx.x;   // longest blocks first
    const int h = blockIdx.y;
    const int kvh = h >> 2;
    const int tid = threadIdx.x, lane = tid & 63, w = tid >> 6;
    const int lrow = lane & 15, lgrp = lane >> 4;
    const int q0 = qb * 64 + w * 16;

    bf16x8 qf[4];
    const unsigned short* qrow = Qb + ((size_t)h * SEQ + q0 + lrow) * HD;
#pragma unroll
    for (int c = 0; c < 4; ++c)
        qf[c] = *(const bf16x8*)(qrow + c * 32 + lgrp * 8);

    float m[4], l[4];
    f32x4 oacc[8];
#pragma unroll
    for (int j = 0; j < 8; ++j) oacc[j] = 0.f;
#pragma unroll
    for (int j = 0; j < 4; ++j) { m[j] = -3.0e38f; l[j] = 0.f; }

    const float scale = 0.08838834764831845f;  // 1/sqrt(128)
    const char* kbase = (const char*)(Kb + (size_t)kvh * SEQ * HD);
    const char* vbase = (const char*)(VTb + (size_t)kvh * HD * SEQ);
    unsigned char* Pl = smem + 32768 + w * 2048;

    for (int t = 0; t <= qb; ++t) {
        __syncthreads();
#pragma unroll
        for (int it = 0; it < 4; ++it) {
            int o = it * 4096 + tid * 16;
            int row = o >> 8, col = o & 255;          // K tile [64][128] (256B rows)
            bf16x8 kv = *(const bf16x8*)(kbase + (size_t)(t * 64 + row) * 256 + col);
            *(bf16x8*)(smem + (o ^ ((row & 7) << 4))) = kv;
            int row2 = o >> 7, col2 = o & 127;        // VT tile [128][64] (128B rows)
            bf16x8 vv = *(const bf16x8*)(vbase + (size_t)row2 * (SEQ * 2) + (size_t)t * 128 + col2);
            *(bf16x8*)(smem + 16384 + (o ^ ((row2 & 7) << 4))) = vv;
        }
        __syncthreads();

        // S = Q K^T
        f32x4 sf[4];
#pragma unroll
        for (int kf = 0; kf < 4; ++kf) sf[kf] = 0.f;
#pragma unroll
        for (int kf = 0; kf < 4; ++kf) {
            int rb = kf * 16 + lrow;
            int rbase = rb * 256;
            int sw = (rb & 7) << 4;
#pragma unroll
            for (int c = 0; c < 4; ++c) {
                bf16x8 kfr = *(const bf16x8*)(smem + rbase + ((c * 64 + lgrp * 16) ^ sw));
                sf[kf] = __builtin_amdgcn_mfma_f32_16x16x32_bf16(qf[c], kfr, sf[kf], 0, 0, 0);
            }
        }
        const bool diag = (t == qb);
        float mx[4] = {-3.0e38f, -3.0e38f, -3.0e38f, -3.0e38f};
#pragma unroll
        for (int kf = 0; kf < 4; ++kf)
#pragma unroll
            for (int j = 0; j < 4; ++j) {
                float v = sf[kf][j] * scale;
                if (diag && (t * 64 + kf * 16 + lrow) > (q0 + lgrp * 4 + j)) v = -3.0e38f;
                sf[kf][j] = v;
                mx[j] = fmaxf(mx[j], v);
            }
#pragma unroll
        for (int off = 1; off < 16; off <<= 1)
#pragma unroll
            for (int j = 0; j < 4; ++j) mx[j] = fmaxf(mx[j], __shfl_xor(mx[j], off));
        float alpha[4], rs[4];
#pragma unroll
        for (int j = 0; j < 4; ++j) {
            float mn = fmaxf(m[j], mx[j]);
            alpha[j] = __expf(m[j] - mn);
            m[j] = mn;
            rs[j] = 0.f;
        }
        // P = exp(s - m) -> per-wave LDS (swizzled [16 q][64 kv] bf16)
#pragma unroll
        for (int kf = 0; kf < 4; ++kf)
#pragma unroll
            for (int j = 0; j < 4; ++j) {
                float p = __expf(sf[kf][j] - m[j]);
                rs[j] += p;
                int q = lgrp * 4 + j;
                int addr = q * 128 + (((kf * 16 + lrow) * 2) ^ ((q & 7) << 4));
                *(unsigned short*)(Pl + addr) = f2bf(p);
            }
#pragma unroll
        for (int off = 1; off < 16; off <<= 1)
#pragma unroll
            for (int j = 0; j < 4; ++j) rs[j] += __shfl_xor(rs[j], off);
#pragma unroll
        for (int j = 0; j < 4; ++j) l[j] = l[j] * alpha[j] + rs[j];
#pragma unroll
        for (int hf = 0; hf < 8; ++hf)
#pragma unroll
            for (int j = 0; j < 4; ++j) oacc[hf][j] *= alpha[j];
        // O += P V
#pragma unroll
        for (int c = 0; c < 2; ++c) {
            int cb = c * 64 + lgrp * 16;
            bf16x8 pf = *(const bf16x8*)(Pl + lrow * 128 + (cb ^ ((lrow & 7) << 4)));
#pragma unroll
            for (int hf = 0; hf < 8; ++hf) {
                int rv = hf * 16 + lrow;
                bf16x8 vf = *(const bf16x8*)(smem + 16384 + rv * 128 + (cb ^ ((rv & 7) << 4)));
                oacc[hf] = __builtin_amdgcn_mfma_f32_16x16x32_bf16(pf, vf, oacc[hf], 0, 0, 0);
            }
        }
    }
#pragma unroll
    for (int hf = 0; hf < 8; ++hf)
#pragma unroll
        for (int j = 0; j < 4; ++j) {
            float v = oacc[hf][j] / l[j];
            int qg = q0 + lgrp * 4 + j;
            O[(size_t)qg * DD + h * HD + hf * 16 + lrow] = f2bf(v);
        }
}

// ---------------- launch ----------------
extern "C" void kernel_launch(void* const* d_in, const int* in_sizes, int n_in,
                              void* d_out, int out_size, void* d_ws, size_t ws_size,
                              hipStream_t stream)
{
    (void)in_sizes; (void)n_in; (void)out_size; (void)ws_size;
    const int* ids = (const int*)d_in[0];
    // d_in[1] = mask (causal, computed inline)
    const float* fc   = (const float*)d_in[2];
    const float* wemb = (const float*)d_in[3];
    const float* wqkv = (const float*)d_in[4];
    const float* wo   = (const float*)d_in[5];
    const float* w1   = (const float*)d_in[6];
    const float* w3   = (const float*)d_in[7];
    const float* w2   = (const float*)d_in[8];
    const float* anw  = (const float*)d_in[9];
    const float* fnw  = (const float*)d_in[10];
    const float* finw = (const float*)d_in[11];
    const float* wh   = (const float*)d_in[12];
    float* out = (float*)d_out;
    char* ws = (char*)d_ws;

    unsigned short* WQKVT = (unsigned short*)(ws);                 // [L][3072][2048] bf16
    unsigned short* WOT   = (unsigned short*)(ws + 25165824);      // [L][2048][2048]
    unsigned short* W13T  = (unsigned short*)(ws + 41943040);      // [L][11264][2048]
    unsigned short* W2T   = (unsigned short*)(ws + 134217728);     // [L][2048][5632]
    unsigned short* WHT   = (unsigned short*)(ws + 180355072);     // [32000][2048]
    float*          X     = (float*)(ws + 311427072);              // [S][D] fp32
    unsigned short* XN    = (unsigned short*)(ws + 328204288);     // [S][D] bf16
    float*          QKV   = (float*)(ws + 336592896);              // [S][3072] fp32
    unsigned short* Qb    = (unsigned short*)(ws + 361758720);     // [NH][S][HD]
    unsigned short* Kb    = (unsigned short*)(ws + 370147328);     // [NKV][S][HD]
    unsigned short* VT    = (unsigned short*)(ws + 372244480);     // [NKV][HD][S]
    unsigned short* AO    = (unsigned short*)(ws + 374341632);     // [S][D] bf16
    float*          H13   = (float*)(ws + 382730240);              // [S][2*FF] fp32
    unsigned short* G     = (unsigned short*)(ws + 475004928);     // [S][FF] bf16

    // weights -> bf16, transposed to [N][K]
    transpose_cast<<<dim3(96, 64, 2), 256, 0, stream>>>(wqkv, WQKVT, 3072, 2048,
        (size_t)2048 * 3072, (size_t)3072 * 2048);
    transpose_cast<<<dim3(64, 64, 2), 256, 0, stream>>>(wo, WOT, 2048, 2048,
        (size_t)2048 * 2048, (size_t)2048 * 2048);
    transpose_cast<<<dim3(176, 64, 2), 256, 0, stream>>>(w1, W13T, 5632, 2048,
        (size_t)2048 * 5632, (size_t)11264 * 2048);
    transpose_cast<<<dim3(176, 64, 2), 256, 0, stream>>>(w3, W13T + (size_t)5632 * 2048, 5632, 2048,
        (size_t)2048 * 5632, (size_t)11264 * 2048);
    transpose_cast<<<dim3(64, 176, 2), 256, 0, stream>>>(w2, W2T, 2048, 5632,
        (size_t)5632 * 2048, (size_t)2048 * 5632);
    transpose_cast<<<dim3(1000, 64, 1), 256, 0, stream>>>(wh, WHT, 32000, 2048, 0, 0);

    embed_gather<<<dim3(SEQ), 256, 0, stream>>>(ids, wemb, X);

    for (int lyr = 0; lyr < NL; ++lyr) {
        const unsigned short* wqkvT_l = WQKVT + (size_t)lyr * 3072 * 2048;
        const unsigned short* woT_l   = WOT   + (size_t)lyr * 2048 * 2048;
        const unsigned short* w13T_l  = W13T  + (size_t)lyr * 11264 * 2048;
        const unsigned short* w2T_l   = W2T   + (size_t)lyr * 2048 * 5632;

        rmsnorm_bf16<<<dim3(SEQ), 256, 0, stream>>>(X, anw + lyr * DD, XN);
        gemm_bf16<<<dim3(24, 16), 256, 0, stream>>>(XN, wqkvT_l, QKV, nullptr, 3072, 2048);
        rope_qk<<<dim3(SEQ, NH + NKV), 64, 0, stream>>>(QKV, fc, Qb, Kb);
        transpose_cast<<<dim3(4, 64, 4), 256, 0, stream>>>(QKV + 2560, VT, 3072, 2048,
            128, (size_t)128 * 2048);
        attn_fwd<<<dim3(32, NH), 256, 0, stream>>>(Qb, Kb, VT, AO);
        gemm_bf16<<<dim3(16, 16), 256, 0, stream>>>(AO, woT_l, X, X, 2048, 2048);
        rmsnorm_bf16<<<dim3(SEQ), 256, 0, stream>>>(X, fnw + lyr * DD, XN);
        gemm_bf16<<<dim3(88, 16), 256, 0, stream>>>(XN, w13T_l, H13, nullptr, 11264, 2048);
        silu_mul<<<dim3(11264), 256, 0, stream>>>(H13, G);
        gemm_bf16<<<dim3(16, 16), 256, 0, stream>>>(G, w2T_l, X, X, 2048, 5632);
    }
    rmsnorm_bf16<<<dim3(SEQ), 256, 0, stream>>>(X, finw, XN);
    gemm_bf16<<<dim3(250, 16), 256, 0, stream>>>(XN, WHT, out, nullptr, 32000, 2048);
}